// Round 10
// baseline (376.294 us; speedup 1.0000x reference)
//
#include <hip/hip_runtime.h>
#include <hip/hip_bf16.h>

// Problem constants
static constexpr int N_   = 100000;
static constexpr int E_   = 1600000;
static constexpr int FIN_ = 128;
static constexpr int DIM_ = 32;
static constexpr int NC_  = 40;
static constexpr int NB_BKT = (N_ + 127) / 128;   // 782 buckets of 128 dst nodes
static constexpr int NCHUNK = 256;                // edge chunks == mega grid size
static constexpr int EPC    = E_ / NCHUNK;        // 6250 edges per chunk (exact)
static constexpr int PROJ_NB = N_ / 32;           // 3125 proj blocks
static constexpr int CS_TASKS = (NB_BKT + 7) / 8; // 98 colscan tasks (8 cols each)

__device__ __forceinline__ int edge_at(const void* e, int is64, long long i) {
    return is64 ? (int)((const long long*)e)[i] : ((const int*)e)[i];
}

__device__ __forceinline__ float bflo(unsigned u) { return __uint_as_float(u << 16); }
__device__ __forceinline__ float bfhi(unsigned u) { return __uint_as_float(u & 0xffff0000u); }

// ---------------------------------------------------------------------------
// Mega build kernel: chist -> colscan -> base-scan -> dscatter, one dispatch.
// 256 blocks x 512 threads; all blocks resident (256 CUs) => grid spin-barrier
// is safe. bar[0]=arrive counter, bar[1]=generation (memset to 0 each launch).
// ---------------------------------------------------------------------------
__device__ __forceinline__ void grid_barrier(int* cnt, int* gen, int phase) {
    __syncthreads();
    if (threadIdx.x == 0) {
        __threadfence();
        int old = atomicAdd(cnt, 1);
        if (old == phase * NCHUNK - 1) {
            __threadfence();
            atomicExch(gen, phase);
        } else {
            while (atomicAdd(gen, 0) < phase) { __builtin_amdgcn_s_sleep(1); }
        }
        __threadfence();
    }
    __syncthreads();
}

__global__ __launch_bounds__(512) void mega_kernel(const void* __restrict__ edge,
                                                   int* __restrict__ ghist,
                                                   int* __restrict__ gcur,
                                                   int* __restrict__ bcnt,
                                                   int* __restrict__ bbase,
                                                   int* __restrict__ offs,
                                                   int* __restrict__ packed,
                                                   int* __restrict__ bar) {
    __shared__ int smem[2816];   // union: lh[782] | tile[2304]+a[256] | a2[256] | cur[782]
    __shared__ int sflag;
    int tid = threadIdx.x;
    int b = blockIdx.x;

    // edge dtype detection (int64 vs int32 layout)
    if (tid < 64) {
        const long long* p_ = (const long long*)edge;
        long long v_ = p_[tid];
        bool bad_ = (v_ < 0 || v_ >= (long long)N_);
        unsigned long long m_ = __ballot(bad_);
        if (tid == 0) sflag = (m_ == 0ull) ? 1 : 0;
    }
    __syncthreads();
    int f = sflag;

    // ---- Phase 1: per-chunk histogram ----
    int* lh = smem;
    for (int i = tid; i < NB_BKT; i += 512) lh[i] = 0;
    __syncthreads();
    {
        int end = b * EPC + EPC;
        for (int e = b * EPC + tid; e < end; e += 512) {
            int d = edge_at(edge, f, (long long)E_ + e);
            atomicAdd(&lh[d >> 7], 1);
        }
    }
    __syncthreads();
    for (int i = tid; i < NB_BKT; i += 512) ghist[b * NB_BKT + i] = lh[i];
    grid_barrier(bar, bar + 1, 1);

    // ---- Phase 2: column scans (blocks 0..97, 8 bucket-cols each) ----
    if (b < CS_TASKS) {
        int* tile = smem;            // 256*9 = 2304 ints
        int k0 = b * 8;
        {
            int kk = tid & 7, r0 = tid >> 3;           // r0 0..63
            for (int p = 0; p < 4; ++p) {
                int bb = r0 + p * 64;
                int k = k0 + kk;
                tile[bb * 9 + kk] = (k < NB_BKT) ? ghist[bb * NB_BKT + k] : 0;
            }
        }
        __syncthreads();
        if (tid < 256) {
            int c = tid >> 5, lane = tid & 31;
            int v[8]; int s = 0;
#pragma unroll
            for (int r = 0; r < 8; ++r) { v[r] = tile[(lane * 8 + r) * 9 + c]; s += v[r]; }
            int incl = s;
#pragma unroll
            for (int off = 1; off < 32; off <<= 1) {
                int u = __shfl_up(incl, off, 32);
                if (lane >= off) incl += u;
            }
            int ex = incl - s;
            int k = k0 + c;
            if (k < NB_BKT) {
                int run = ex;
#pragma unroll
                for (int r = 0; r < 8; ++r) {
                    int bb = lane * 8 + r;
                    gcur[bb * NB_BKT + k] = run;
                    run += v[r];
                }
                if (lane == 31) bcnt[k] = run;
            }
        }
    }
    grid_barrier(bar, bar + 1, 2);

    // ---- Phase 3: block 0 scans bucket totals -> bbase, offs[N] ----
    if (b == 0) {
        int* a = smem;               // 256 ints
        int b4[4]; int base4 = tid * 4; int t4 = 0;
        if (tid < 256) {
#pragma unroll
            for (int j = 0; j < 4; ++j) { int i = base4 + j; b4[j] = (i < NB_BKT) ? bcnt[i] : 0; t4 += b4[j]; }
            a[tid] = t4;
        }
        __syncthreads();
        for (int off = 1; off < 256; off <<= 1) {
            int u = 0;
            if (tid < 256) u = a[tid] + ((tid >= off) ? a[tid - off] : 0);
            __syncthreads();
            if (tid < 256) a[tid] = u;
            __syncthreads();
        }
        if (tid < 256) {
            int g = a[tid] - t4;
#pragma unroll
            for (int j = 0; j < 4; ++j) { int i = base4 + j; if (i < NB_BKT) bbase[i] = g; g += b4[j]; }
        }
        if (tid == 255) offs[N_] = a[255];   // == E_
    }
    grid_barrier(bar, bar + 1, 3);

    // ---- Phase 4: deterministic scatter, cursors in LDS ----
    int* cur = smem;
    for (int k = tid; k < NB_BKT; k += 512) cur[k] = bbase[k] + gcur[b * NB_BKT + k];
    __syncthreads();
    {
        int end = b * EPC + EPC;
        for (int e = b * EPC + tid; e < end; e += 512) {
            int s = edge_at(edge, f, e);
            int d = edge_at(edge, f, (long long)E_ + e);
            int pos = atomicAdd(&cur[d >> 7], 1);     // LDS int atomic
            packed[pos] = s | ((d & 127) << 17);      // N < 2^17
        }
    }
}

// ---------------------------------------------------------------------------
// bsort ∥ proj: blocks [0,782): per-bucket counting sort -> offs[] + csr[];
// blocks [782, 782+3125): yh = bf16(x @ w1a).
// ---------------------------------------------------------------------------
__global__ __launch_bounds__(256) void fat_kernel(const int* __restrict__ bcnt,
                                                  const int* __restrict__ bbase,
                                                  const int* __restrict__ packed,
                                                  int* __restrict__ offs,
                                                  int* __restrict__ csr,
                                                  const float* __restrict__ x,
                                                  const float* __restrict__ w,
                                                  __hip_bfloat16* __restrict__ yh) {
    __shared__ __align__(16) char smem[32768];
    int tid = threadIdx.x;
    if (blockIdx.x < NB_BKT) {
        int* c   = (int*)smem;
        int* cur = (int*)smem + 128;
        int b = blockIdx.x;
        int beg = bbase[b], cnt = bcnt[b];
        if (tid < 128) c[tid] = 0;
        __syncthreads();
        for (int i = tid; i < cnt; i += 256)
            atomicAdd(&c[packed[beg + i] >> 17], 1);
        __syncthreads();
        int myv = (tid < 128) ? c[tid] : 0;
        for (int off = 1; off < 128; off <<= 1) {
            int t = 0;
            if (tid < 128) t = c[tid] + ((tid >= off) ? c[tid - off] : 0);
            __syncthreads();
            if (tid < 128) c[tid] = t;
            __syncthreads();
        }
        if (tid < 128) {
            int ex = c[tid] - myv;
            cur[tid] = ex;
            int node = b * 128 + tid;
            if (node < N_) offs[node] = beg + ex;
        }
        __syncthreads();
        for (int i = tid; i < cnt; i += 256) {
            int v = packed[beg + i];
            int p = atomicAdd(&cur[v >> 17], 1);
            csr[beg + p] = v & 0x1FFFF;
        }
    } else {
        float* wsm = (float*)smem;               // 16 KB
        float* xs  = (float*)(smem + 16384);     // 16 KB
        const float4* w4 = (const float4*)w;
        float4* ws4 = (float4*)wsm;
        for (int i = tid; i < FIN_ * DIM_ / 4; i += 256) ws4[i] = w4[i];

        int nodeBase = (blockIdx.x - NB_BKT) * 32;
        const float4* x4 = (const float4*)(x + (size_t)nodeBase * FIN_);
        float4* xs4 = (float4*)xs;
        for (int i = tid; i < 32 * FIN_ / 4; i += 256) xs4[i] = x4[i];
        __syncthreads();

        int d = tid & 31, ns = tid >> 5;
        for (int rep = 0; rep < 4; ++rep) {
            int node = ns + rep * 8;
            float acc = 0.f;
#pragma unroll 4
            for (int k = 0; k < FIN_; ++k) acc += xs[node * FIN_ + k] * wsm[k * DIM_ + d];
            yh[(size_t)(nodeBase + node) * DIM_ + d] = __float2bfloat16(acc);
        }
    }
}

// ---------------------------------------------------------------------------
// Gather (R6-proven shape): 8 lanes x 8B (uint2) per 64B row, 4-wide unroll.
// Non-temporal csr loads keep L2 free for vec. acc starts from SELF row.
// ---------------------------------------------------------------------------
__device__ __forceinline__ void gather_row(const int* __restrict__ csr,
                                           const char* __restrict__ vb,
                                           int beg, int end, int loff,
                                           float& a0, float& a1, float& a2, float& a3) {
    int i = beg;
    for (; i + 3 < end; i += 4) {
        int s0 = __builtin_nontemporal_load(csr + i);
        int s1 = __builtin_nontemporal_load(csr + i + 1);
        int s2 = __builtin_nontemporal_load(csr + i + 2);
        int s3 = __builtin_nontemporal_load(csr + i + 3);
        uint2 u0 = *(const uint2*)(vb + (((size_t)s0) << 6) + loff);
        uint2 u1 = *(const uint2*)(vb + (((size_t)s1) << 6) + loff);
        uint2 u2 = *(const uint2*)(vb + (((size_t)s2) << 6) + loff);
        uint2 u3 = *(const uint2*)(vb + (((size_t)s3) << 6) + loff);
        a0 += (bflo(u0.x) + bflo(u1.x)) + (bflo(u2.x) + bflo(u3.x));
        a1 += (bfhi(u0.x) + bfhi(u1.x)) + (bfhi(u2.x) + bfhi(u3.x));
        a2 += (bflo(u0.y) + bflo(u1.y)) + (bflo(u2.y) + bflo(u3.y));
        a3 += (bfhi(u0.y) + bfhi(u1.y)) + (bfhi(u2.y) + bfhi(u3.y));
    }
    for (; i < end; ++i) {
        int s0 = __builtin_nontemporal_load(csr + i);
        uint2 u0 = *(const uint2*)(vb + (((size_t)s0) << 6) + loff);
        a0 += bflo(u0.x); a1 += bfhi(u0.x); a2 += bflo(u0.y); a3 += bfhi(u0.y);
    }
}

// Degree-balanced permutation: rank 32 nodes by degree, deal round-robin to
// the 4 waves (slot = (r&3)*8 + (r>>2)) so each wave gets a heavy+light mix.
#define BUILD_PERM(offs_)                                               \
    if (tid < 32) degs[tid] = offs_[blockIdx.x * 32 + tid + 1] -        \
                              offs_[blockIdx.x * 32 + tid];             \
    __syncthreads();                                                    \
    if (tid < 32) {                                                     \
        int mydeg = degs[tid]; int r = 0;                               \
        for (int j = 0; j < 32; ++j) {                                  \
            int dj = degs[j];                                           \
            r += (dj > mydeg) || (dj == mydeg && j < tid);              \
        }                                                               \
        perm[(r & 3) * 8 + (r >> 2)] = tid;                             \
    }                                                                   \
    __syncthreads();

// ---------------------------------------------------------------------------
// Fused 1: gather(self+neighbors) -> u=relu(A+b1a) -> hb=bn1(relu(u@w1b+b1b))
// -> zh=bf16(hb@w2a).
// ---------------------------------------------------------------------------
__global__ __launch_bounds__(256) void aggmlp1_kernel(const int* __restrict__ offs,
                                                      const int* __restrict__ csr,
                                                      const __hip_bfloat16* __restrict__ yh,
                                                      const float* __restrict__ b1a,
                                                      const float* __restrict__ w1b,
                                                      const float* __restrict__ b1b,
                                                      const float* __restrict__ g1,
                                                      const float* __restrict__ be1,
                                                      const float* __restrict__ m1,
                                                      const float* __restrict__ v1,
                                                      const float* __restrict__ w2a,
                                                      __hip_bfloat16* __restrict__ zh) {
    __shared__ float A[32 * 33];
    __shared__ float B[32 * 33];
    __shared__ float w1s[DIM_ * DIM_];
    __shared__ float w2s[DIM_ * DIM_];
    __shared__ int degs[32];
    __shared__ int perm[32];
    int tid = threadIdx.x;
    for (int i = tid; i < DIM_ * DIM_; i += 256) { w1s[i] = w1b[i]; w2s[i] = w2a[i]; }

    BUILD_PERM(offs)

    int nl = tid >> 3, lane = tid & 7;
    int j = perm[nl];
    int node = blockIdx.x * 32 + j;
    int beg = offs[node], end = offs[node + 1];
    const char* vb = (const char*)yh;
    int loff = lane << 3;
    uint2 us = *(const uint2*)(vb + (((size_t)node) << 6) + loff);   // self row
    float a0 = bflo(us.x), a1 = bfhi(us.x), a2 = bflo(us.y), a3 = bfhi(us.y);
    gather_row(csr, vb, beg, end, loff, a0, a1, a2, a3);
    {
        float* p = &A[j * 33 + lane * 4];
        p[0] = a0; p[1] = a1; p[2] = a2; p[3] = a3;
    }
    __syncthreads();

    int d = tid & 31, ng = tid >> 5;
    size_t gbase = (size_t)blockIdx.x * 32 * DIM_;

    // u = relu(A + b1a)   (A already holds agg + self)
#pragma unroll
    for (int r = 0; r < 4; ++r) {
        int n = r * 8 + ng;
        A[n * 33 + d] = fmaxf(A[n * 33 + d] + b1a[d], 0.f);
    }
    __syncthreads();

    float sc1 = g1[d] * rsqrtf(v1[d] + 1e-5f);
    float sh1 = be1[d] - m1[d] * sc1;

    // hb = bn1(relu(u @ w1b + b1b))
#pragma unroll
    for (int r = 0; r < 4; ++r) {
        int n = r * 8 + ng;
        float s = b1b[d];
#pragma unroll
        for (int k = 0; k < DIM_; ++k) s += A[n * 33 + k] * w1s[k * DIM_ + d];
        B[n * 33 + d] = fmaxf(s, 0.f) * sc1 + sh1;
    }
    __syncthreads();

    // z = hb @ w2a -> bf16
#pragma unroll
    for (int r = 0; r < 4; ++r) {
        int n = r * 8 + ng;
        float s = 0.f;
#pragma unroll
        for (int k = 0; k < DIM_; ++k) s += B[n * 33 + k] * w2s[k * DIM_ + d];
        zh[gbase + n * DIM_ + d] = __float2bfloat16(s);
    }
}

// ---------------------------------------------------------------------------
// Fused 2: gather(self+neighbors) -> u=relu(A+b2a) -> hb=bn2(u@w2b+b2b) ->
// f=relu(hb@fc1w+f1b) -> logits -> log_softmax (non-temporal out stores).
// ---------------------------------------------------------------------------
__global__ __launch_bounds__(256) void aggmlp2_kernel(const int* __restrict__ offs,
                                                      const int* __restrict__ csr,
                                                      const __hip_bfloat16* __restrict__ zh,
                                                      const float* __restrict__ b2a,
                                                      const float* __restrict__ w2b,
                                                      const float* __restrict__ b2b,
                                                      const float* __restrict__ g2,
                                                      const float* __restrict__ be2,
                                                      const float* __restrict__ m2,
                                                      const float* __restrict__ v2,
                                                      const float* __restrict__ f1w,
                                                      const float* __restrict__ f1b,
                                                      const float* __restrict__ f2w,
                                                      const float* __restrict__ f2b,
                                                      float* __restrict__ out) {
    __shared__ float A[32 * 33];
    __shared__ float BC[DIM_ * NC_];   // B (hb) then wC
    __shared__ float wA[DIM_ * DIM_];
    __shared__ float wB[DIM_ * DIM_];
    __shared__ int degs[32];
    __shared__ int perm[32];
    int tid = threadIdx.x;
    for (int i = tid; i < DIM_ * DIM_; i += 256) { wA[i] = w2b[i]; wB[i] = f1w[i]; }

    BUILD_PERM(offs)

    int nl = tid >> 3, lane = tid & 7;
    int j = perm[nl];
    int node = blockIdx.x * 32 + j;
    int beg = offs[node], end = offs[node + 1];
    const char* vb = (const char*)zh;
    int loff = lane << 3;
    uint2 us = *(const uint2*)(vb + (((size_t)node) << 6) + loff);   // self row
    float a0 = bflo(us.x), a1 = bfhi(us.x), a2 = bflo(us.y), a3 = bfhi(us.y);
    gather_row(csr, vb, beg, end, loff, a0, a1, a2, a3);
    {
        float* p = &A[j * 33 + lane * 4];
        p[0] = a0; p[1] = a1; p[2] = a2; p[3] = a3;
    }
    __syncthreads();

    int d = tid & 31, ng = tid >> 5;

    // u2 = relu(A + b2a)
#pragma unroll
    for (int r = 0; r < 4; ++r) {
        int n = r * 8 + ng;
        A[n * 33 + d] = fmaxf(A[n * 33 + d] + b2a[d], 0.f);
    }
    __syncthreads();

    float sc2 = g2[d] * rsqrtf(v2[d] + 1e-5f);
    float sh2 = be2[d] - m2[d] * sc2;

    // hb = bn2(u2 @ w2b + b2b)   (no relu between conv2 and bn2)
#pragma unroll
    for (int r = 0; r < 4; ++r) {
        int n = r * 8 + ng;
        float s = b2b[d];
#pragma unroll
        for (int k = 0; k < DIM_; ++k) s += A[n * 33 + k] * wA[k * DIM_ + d];
        BC[n * 33 + d] = s * sc2 + sh2;
    }
    __syncthreads();

    // f = relu(hb @ fc1w + fc1b) -> overwrite A
#pragma unroll
    for (int r = 0; r < 4; ++r) {
        int n = r * 8 + ng;
        float s = f1b[d];
#pragma unroll
        for (int k = 0; k < DIM_; ++k) s += BC[n * 33 + k] * wB[k * DIM_ + d];
        A[n * 33 + d] = fmaxf(s, 0.f);
    }
    __syncthreads();
    for (int i = tid; i < DIM_ * NC_; i += 256) BC[i] = f2w[i];   // wC over dead B
    __syncthreads();

    int c2 = 32 + (d & 7);
#pragma unroll
    for (int r = 0; r < 4; ++r) {
        int n = r * 8 + ng;
        float l0 = f2b[d];
        float l1 = f2b[c2];
#pragma unroll
        for (int k = 0; k < DIM_; ++k) {
            float fv = A[n * 33 + k];
            l0 += fv * BC[k * NC_ + d];
            l1 += fv * BC[k * NC_ + c2];
        }
        float mx = fmaxf(l0, l1);
#pragma unroll
        for (int off = 16; off; off >>= 1) mx = fmaxf(mx, __shfl_xor(mx, off));
        float se = __expf(l0 - mx) + ((d < 8) ? __expf(l1 - mx) : 0.f);
#pragma unroll
        for (int off = 16; off; off >>= 1) se += __shfl_xor(se, off);
        float lse = mx + __logf(se);
        size_t ob = (size_t)(blockIdx.x * 32 + n) * NC_;
        __builtin_nontemporal_store(l0 - lse, &out[ob + d]);
        if (d < 8) __builtin_nontemporal_store(l1 - lse, &out[ob + 32 + d]);
    }
}

// ---------------------------------------------------------------------------
extern "C" void kernel_launch(void* const* d_in, const int* in_sizes, int n_in,
                              void* d_out, int out_size, void* d_ws, size_t ws_size,
                              hipStream_t stream) {
    const float* x   = (const float*)d_in[0];
    const void*  edg = d_in[1];
    const float* w1a = (const float*)d_in[2];
    const float* b1a = (const float*)d_in[3];
    const float* w1b = (const float*)d_in[4];
    const float* b1b = (const float*)d_in[5];
    const float* w2a = (const float*)d_in[6];
    const float* b2a = (const float*)d_in[7];
    const float* w2b = (const float*)d_in[8];
    const float* b2b = (const float*)d_in[9];
    const float* g1  = (const float*)d_in[10];
    const float* be1 = (const float*)d_in[11];
    const float* m1  = (const float*)d_in[12];
    const float* v1  = (const float*)d_in[13];
    const float* g2  = (const float*)d_in[14];
    const float* be2 = (const float*)d_in[15];
    const float* m2  = (const float*)d_in[16];
    const float* v2  = (const float*)d_in[17];
    const float* f1w = (const float*)d_in[18];
    const float* f1b = (const float*)d_in[19];
    const float* f2w = (const float*)d_in[20];
    const float* f2b = (const float*)d_in[21];
    float* out = (float*)d_out;

    // Workspace layout (byte offsets, 128B-aligned)
    char* ws = (char*)d_ws;
    int* bar    = (int*)ws;                      // 2 ints (memset each launch)
    int* bcnt   = (int*)(ws + 256);              // 782 ints (pad 3328)
    int* bbase  = (int*)(ws + 3584);             // 782 ints (pad 3328)
    int* ghist  = (int*)(ws + 6912);             // 256*782 ints
    int* gcur   = (int*)(ws + 807680);           // 256*782 ints (chunk-major)
    int* offs   = (int*)(ws + 1608448);          // N+1 ints (pad 400128)
    int* packed = (int*)(ws + 2008576);          // E ints
    int* csr    = (int*)(ws + 8408576);          // E ints
    __hip_bfloat16* yh = (__hip_bfloat16*)(ws + 14808576);  // N*DIM bf16
    __hip_bfloat16* zh = (__hip_bfloat16*)(ws + 21208576);  // N*DIM bf16

    hipMemsetAsync(bar, 0, 16, stream);

    // ---- Build (one fused dispatch: hist + scans + scatter) ----
    mega_kernel<<<NCHUNK, 512, 0, stream>>>(edg, ghist, gcur, bcnt, bbase, offs,
                                            packed, bar);
    // ---- bsort ∥ proj ----
    fat_kernel<<<NB_BKT + PROJ_NB, 256, 0, stream>>>(bcnt, bbase, packed, offs, csr,
                                                     x, w1a, yh);

    // ---- Layer 1 (proj folded pre-aggregation) ----
    aggmlp1_kernel<<<N_ / 32, 256, 0, stream>>>(offs, csr, yh, b1a, w1b, b1b,
                                                g1, be1, m1, v1, w2a, zh);

    // ---- Layer 2 + head (w2a folded pre-aggregation) ----
    aggmlp2_kernel<<<N_ / 32, 256, 0, stream>>>(offs, csr, zh, b2a, w2b, b2b,
                                                g2, be2, m2, v2, f1w, f1b,
                                                f2w, f2b, out);
}